// Round 9
// baseline (205.988 us; speedup 1.0000x reference)
//
#include <hip/hip_runtime.h>

// InfiniAttention — Round 9: R8 structure + BK=64 K-steps (half the barrier drains),
// k7b atomics -> 4 full-K blocks, kC chunk-KV on 128x128 tiles, vectorized prefix.

#define HIDDEN 1024
#define DMEM 256
#define BATCH 4
#define SEQ 1024
#define MTOT (BATCH * SEQ)      // 4096
#define CHUNK 128
#define NCH (SEQ / CHUNK)       // 8
#define NCHT (BATCH * NCH)      // 32
#define EPSF 1e-6f

typedef __bf16 bf16x8 __attribute__((ext_vector_type(8)));
typedef __bf16 bf16x4 __attribute__((ext_vector_type(4)));
typedef float f32x4 __attribute__((ext_vector_type(4)));

#define GL_LDS(g, l)                                                                   \
  __builtin_amdgcn_global_load_lds((const __attribute__((address_space(1))) void*)(g), \
                                   (__attribute__((address_space(3))) void*)(l), 16, 0, 0)

__device__ __forceinline__ float elu1(float x) { return x > 0.f ? x + 1.f : __expf(x); }

// Stage a 128-row x 64-col tile as two 32-col slabs (slab h at sm + h*4096).
__device__ __forceinline__ void stage128(const __bf16* p, long ld, int k0, __bf16* sm,
                                         int wave) {
  GL_LDS(p + k0, sm + wave * 512);
  GL_LDS(p + (size_t)64 * ld + k0, sm + 2048 + wave * 512);
  GL_LDS(p + k0 + 32, sm + 4096 + wave * 512);
  GL_LDS(p + (size_t)64 * ld + k0 + 32, sm + 4096 + 2048 + wave * 512);
}
// Stage a 64-row x 64-col tile as two slabs (slab h at sm + h*2048).
__device__ __forceinline__ void stage64(const __bf16* p, int k0, __bf16* sm, int wave) {
  GL_LDS(p + k0, sm + wave * 512);
  GL_LDS(p + k0 + 32, sm + 2048 + wave * 512);
}

// 128x128 tile, BK=64. aptr/bptr pre-offset by (tid>>2) rows + (tid&3)*8 cols.
__device__ __forceinline__ void gemm128_bk64(const __bf16* aptr, long lda, const __bf16* bptr,
                                             long ldb, int klen, __bf16* smA, __bf16* smB,
                                             int wave, int wr, int wc, int quad, int l16,
                                             f32x4 (&acc)[4][4]) {
  for (int k0 = 0; k0 < klen; k0 += 64) {
    stage128(aptr, lda, k0, smA, wave);
    stage128(bptr, ldb, k0, smB, wave);
    __syncthreads();
#pragma unroll
    for (int h = 0; h < 2; ++h) {
      bf16x8 aF[4], bF[4];
#pragma unroll
      for (int i = 0; i < 4; ++i)
        aF[i] = *reinterpret_cast<const bf16x8*>(smA + h * 4096 +
                                                 (wr * 64 + i * 16 + l16) * 32 + quad * 8);
#pragma unroll
      for (int j = 0; j < 4; ++j)
        bF[j] = *reinterpret_cast<const bf16x8*>(smB + h * 4096 +
                                                 (wc * 64 + j * 16 + l16) * 32 + quad * 8);
#pragma unroll
      for (int i = 0; i < 4; ++i)
#pragma unroll
        for (int j = 0; j < 4; ++j)
          acc[i][j] = __builtin_amdgcn_mfma_f32_16x16x32_bf16(aF[i], bF[j], acc[i][j], 0, 0, 0);
    }
    __syncthreads();
  }
}

// 64x128 tile, BK=64.
__device__ __forceinline__ void gemm64_bk64(const __bf16* aptr, const __bf16* bptr, long ldb,
                                            int klen, __bf16* smA, __bf16* smB, int wave,
                                            int wr, int wc, int quad, int l16,
                                            f32x4 (&acc)[2][4]) {
  for (int k0 = 0; k0 < klen; k0 += 64) {
    stage64(aptr, k0, smA, wave);
    stage128(bptr, ldb, k0, smB, wave);
    __syncthreads();
#pragma unroll
    for (int h = 0; h < 2; ++h) {
      bf16x8 aF[2], bF[4];
#pragma unroll
      for (int i = 0; i < 2; ++i)
        aF[i] = *reinterpret_cast<const bf16x8*>(smA + h * 2048 +
                                                 (wr * 32 + i * 16 + l16) * 32 + quad * 8);
#pragma unroll
      for (int j = 0; j < 4; ++j)
        bF[j] = *reinterpret_cast<const bf16x8*>(smB + h * 4096 +
                                                 (wc * 64 + j * 16 + l16) * 32 + quad * 8);
#pragma unroll
      for (int i = 0; i < 2; ++i)
#pragma unroll
        for (int j = 0; j < 4; ++j)
          acc[i][j] = __builtin_amdgcn_mfma_f32_16x16x32_bf16(aF[i], bF[j], acc[i][j], 0, 0, 0);
    }
    __syncthreads();
  }
}

// ---------------- kprep: casts + memT (seed removed; k7b writes mem directly) -----------
__global__ void kprep(const float* __restrict__ hs, const float* __restrict__ wq,
                      const float* __restrict__ wk, const float* __restrict__ wv,
                      const float* __restrict__ wo, const float* __restrict__ mem,
                      __bf16* __restrict__ hsb, __bf16* __restrict__ wqkvb,
                      __bf16* __restrict__ wob, __bf16* __restrict__ memT) {
  __shared__ float s[64][65];
  int b = blockIdx.x, tid = threadIdx.x;
  if (b < 4096) {
    int i = b * 256 + tid;
    float4 f = reinterpret_cast<const float4*>(hs)[i];
    bf16x4 h = {(__bf16)f.x, (__bf16)f.y, (__bf16)f.z, (__bf16)f.w};
    reinterpret_cast<bf16x4*>(hsb)[i] = h;
  } else if (b < 5120) {
    int y = (b - 4096) >> 8;
    const float* src = (y == 0) ? wq : (y == 1) ? wk : (y == 2) ? wv : wo;
    __bf16* dst = (y < 3) ? wqkvb + (size_t)y * (DMEM * HIDDEN) : wob;
    int i = ((b - 4096) & 255) * 256 + tid;
    float4 f = reinterpret_cast<const float4*>(src)[i];
    bf16x4 h = {(__bf16)f.x, (__bf16)f.y, (__bf16)f.z, (__bf16)f.w};
    reinterpret_cast<bf16x4*>(dst)[i] = h;
  } else {
    int t = b - 5120;
    int bx = t & 3, by = t >> 2;
    int r0 = tid >> 6, col = tid & 63;
#pragma unroll
    for (int it = 0; it < 16; ++it) {
      int row = it * 4 + r0;
      s[row][col] = mem[(size_t)(by * 64 + row) * DMEM + bx * 64 + col];
    }
    __syncthreads();
#pragma unroll
    for (int it = 0; it < 16; ++it) {
      int row = it * 4 + r0;
      memT[(size_t)(bx * 64 + row) * DMEM + by * 64 + col] = (__bf16)s[col][row];
    }
  }
}

// ---------------- K1: fused QKV projection, 128x128 BK=64 ----------------
__global__ __launch_bounds__(256) void k1_qkv_mfma(
    const __bf16* __restrict__ X, const __bf16* __restrict__ W, __bf16* __restrict__ sqb,
    __bf16* __restrict__ skb, __bf16* __restrict__ skT, __bf16* __restrict__ vT) {
  __shared__ __bf16 As[8192];
  __shared__ __bf16 Bs[8192];
  int tid = threadIdx.x;
  int lane = tid & 63, wave = tid >> 6;
  int m0 = blockIdx.x * 128;
  int by = blockIdx.y;
  int wsel = by >> 1, n0 = (by & 1) * 128;
  const __bf16* aptr = X + (size_t)(m0 + (tid >> 2)) * HIDDEN + ((tid & 3) << 3);
  const __bf16* bptr = W + (size_t)(by * 128 + (tid >> 2)) * HIDDEN + ((tid & 3) << 3);
  int wr = wave >> 1, wc = wave & 1, quad = lane >> 4, l16 = lane & 15;
  f32x4 acc[4][4] = {};
  gemm128_bk64(aptr, HIDDEN, bptr, HIDDEN, HIDDEN, As, Bs, wave, wr, wc, quad, l16, acc);
#pragma unroll
  for (int i = 0; i < 4; ++i)
#pragma unroll
    for (int j = 0; j < 4; ++j) {
      int mb = m0 + wr * 64 + i * 16 + quad * 4;
      int n = n0 + wc * 64 + j * 16 + l16;
      if (wsel == 0) {
#pragma unroll
        for (int r = 0; r < 4; ++r) sqb[(size_t)(mb + r) * DMEM + n] = (__bf16)elu1(acc[i][j][r]);
      } else if (wsel == 1) {
        bf16x4 t;
#pragma unroll
        for (int r = 0; r < 4; ++r) {
          float v = elu1(acc[i][j][r]);
          skb[(size_t)(mb + r) * DMEM + n] = (__bf16)v;
          t[r] = (__bf16)v;
        }
        *reinterpret_cast<bf16x4*>(skT + (size_t)n * MTOT + mb) = t;
      } else {
        bf16x4 t;
#pragma unroll
        for (int r = 0; r < 4; ++r) t[r] = (__bf16)acc[i][j][r];
        *reinterpret_cast<bf16x4*>(vT + (size_t)n * MTOT + mb) = t;
      }
    }
}

// ------- kC: chunk-KV 128x128 (y<4) + causal scores (y=4,5) + ksum (y=6). grid (32,7) ------
__global__ __launch_bounds__(256) void kC(const __bf16* __restrict__ vT,
                                          const __bf16* __restrict__ skT,
                                          const __bf16* __restrict__ sqb,
                                          const __bf16* __restrict__ skb,
                                          __bf16* __restrict__ kvcT, __bf16* __restrict__ scb,
                                          float* __restrict__ ksc) {
  __shared__ __bf16 As[8192];
  __shared__ __bf16 Bs[8192];
  int tid = threadIdx.x;
  int c = blockIdx.x;
  int y = blockIdx.y;
  if (y == 6) {
    int d = tid;
    float s = 0.f;
    for (int i = 0; i < CHUNK; ++i) s += (float)skb[(size_t)(c * CHUNK + i) * DMEM + d];
    ksc[c * DMEM + d] = s;
    return;
  }
  int lane = tid & 63, wave = tid >> 6;
  int wr = wave >> 1, wc = wave & 1, quad = lane >> 4, l16 = lane & 15;
  if (y < 4) {  // kvcT[c][e][d] = sum_s vT[e,s]*skT[d,s], 128x128 tile
    int e0 = (y >> 1) * 128, d0 = (y & 1) * 128;
    const __bf16* aptr = vT + (size_t)(e0 + (tid >> 2)) * MTOT + c * CHUNK + ((tid & 3) << 3);
    const __bf16* bptr = skT + (size_t)(d0 + (tid >> 2)) * MTOT + c * CHUNK + ((tid & 3) << 3);
    f32x4 acc[4][4] = {};
    gemm128_bk64(aptr, MTOT, bptr, MTOT, CHUNK, As, Bs, wave, wr, wc, quad, l16, acc);
#pragma unroll
    for (int i = 0; i < 4; ++i)
#pragma unroll
      for (int j = 0; j < 4; ++j)
#pragma unroll
        for (int r = 0; r < 4; ++r) {
          int e = e0 + wr * 64 + i * 16 + quad * 4 + r;
          int d = d0 + wc * 64 + j * 16 + l16;
          kvcT[(size_t)c * DMEM * DMEM + (size_t)e * DMEM + d] = (__bf16)acc[i][j][r];
        }
  } else {  // causal scores, i0 = (y-4)*64
    int i0 = (y - 4) * 64;
    const __bf16* aptr = sqb + (size_t)(c * CHUNK + i0 + (tid >> 2)) * DMEM + ((tid & 3) << 3);
    const __bf16* bptr = skb + (size_t)(c * CHUNK + (tid >> 2)) * DMEM + ((tid & 3) << 3);
    f32x4 acc[2][4] = {};
    gemm64_bk64(aptr, bptr, DMEM, DMEM, As, Bs, wave, wr, wc, quad, l16, acc);
#pragma unroll
    for (int i = 0; i < 2; ++i)
#pragma unroll
      for (int j = 0; j < 4; ++j)
#pragma unroll
        for (int r = 0; r < 4; ++r) {
          int ii = i0 + wr * 32 + i * 16 + quad * 4 + r;
          int jj = wc * 64 + j * 16 + l16;
          scb[(size_t)c * CHUNK * CHUNK + (size_t)ii * CHUNK + jj] =
              (jj <= ii) ? (__bf16)acc[i][j][r] : (__bf16)0.f;
        }
  }
}

// ---------------- kD: vectorized prefix (vt<128) + row scalars (vt>=128). grid 1152 -------
__global__ __launch_bounds__(256) void kD(const __bf16* __restrict__ kvcT,
                                          __bf16* __restrict__ kvpT,
                                          const float* __restrict__ ksc,
                                          const __bf16* __restrict__ scb,
                                          const __bf16* __restrict__ sqb,
                                          const __bf16* __restrict__ skb,
                                          const float* __restrict__ mnorm,
                                          float* __restrict__ den, float* __restrict__ qn,
                                          float* __restrict__ kn) {
  int vt = blockIdx.x;
  int tid = threadIdx.x;
  if (vt < 128) {
    int batch = vt >> 5;
    size_t idx8 = (size_t)(((vt & 31) * 256 + tid)) * 8;
    float run[8] = {};
    for (int c = 0; c < NCH; ++c) {
      size_t off = (size_t)(batch * NCH + c) * DMEM * DMEM + idx8;
      bf16x8 t = *reinterpret_cast<const bf16x8*>(kvcT + off);
      bf16x8 o;
#pragma unroll
      for (int r = 0; r < 8; ++r) o[r] = (__bf16)run[r];
      *reinterpret_cast<bf16x8*>(kvpT + off) = o;
#pragma unroll
      for (int r = 0; r < 8; ++r) run[r] += (float)t[r];
    }
  } else {
    int wave = tid >> 6, lane = tid & 63;
    int m = (vt - 128) * 4 + wave;
    int c = m >> 7;
    int i = m & 127;
    int cb = c & ~7;
    float s_sc = 0.f, s_d2 = 0.f, s_qn = 0.f, s_kn = 0.f;
    for (int j = lane; j < CHUNK; j += 64)
      s_sc += (float)scb[(size_t)c * CHUNK * CHUNK + (size_t)i * CHUNK + j];
    for (int d = lane; d < DMEM; d += 64) {
      float q = (float)sqb[(size_t)m * DMEM + d];
      float k = (float)skb[(size_t)m * DMEM + d];
      float kp = 0.f;
      for (int cc = cb; cc < c; ++cc) kp += ksc[cc * DMEM + d];
      s_d2 += q * kp;
      s_qn += q * mnorm[d];
      s_kn += k * mnorm[d];
    }
#pragma unroll
    for (int off = 32; off > 0; off >>= 1) {
      s_sc += __shfl_down(s_sc, off);
      s_d2 += __shfl_down(s_d2, off);
      s_qn += __shfl_down(s_qn, off);
      s_kn += __shfl_down(s_kn, off);
    }
    if (lane == 0) {
      den[m] = s_sc + s_d2;
      qn[m] = s_qn;
      kn[m] = s_kn;
    }
  }
}

// ---------------- kE: combine (bid<128) + delta-v (128..191). grid 192 ----------------
__global__ __launch_bounds__(256) void kE(const __bf16* __restrict__ scb,
                                          const __bf16* __restrict__ sqb,
                                          const __bf16* __restrict__ skb,
                                          const __bf16* __restrict__ vT,
                                          const __bf16* __restrict__ kvpT,
                                          const __bf16* __restrict__ memT,
                                          const float* __restrict__ den,
                                          const float* __restrict__ qn,
                                          const float* __restrict__ kn,
                                          const float* __restrict__ gate,
                                          const float* __restrict__ mnorm,
                                          __bf16* __restrict__ combb, __bf16* __restrict__ dvT) {
  __shared__ __bf16 As[8192];
  __shared__ __bf16 B1s[8192];
  __shared__ __bf16 B2s[8192];
  __shared__ float flagsh;
  int tid = threadIdx.x;
  int lane = tid & 63, wave = tid >> 6;
  int wr = wave >> 1, wc = wave & 1, quad = lane >> 4, l16 = lane & 15;
  int bid = blockIdx.x;
  if (bid < 128) {  // combine
    if (tid == 0) {
      float s = 0.f;
      for (int d = 0; d < DMEM; ++d) s += mnorm[d];
      flagsh = (s < EPSF) ? 0.f : 1.f;
    }
    __syncthreads();
    float fl = flagsh;
    __syncthreads();
    int c = bid >> 2, yy = bid & 3;
    int i0 = (yy >> 1) * 64, e0 = (yy & 1) * 128;
    f32x4 acc_loc[2][4] = {};
    f32x4 acc_mem[2][4] = {};
    {  // phase 1: scores @ v (K=128)
      const __bf16* aptr =
          scb + (size_t)c * CHUNK * CHUNK + (size_t)(i0 + (tid >> 2)) * CHUNK + ((tid & 3) << 3);
      const __bf16* bptr = vT + (size_t)(e0 + (tid >> 2)) * MTOT + c * CHUNK + ((tid & 3) << 3);
      gemm64_bk64(aptr, bptr, MTOT, CHUNK, As, B1s, wave, wr, wc, quad, l16, acc_loc);
    }
    {  // phase 2: sq @ kvp + sq @ memT (K=256, dual B)
      const __bf16* aptr = sqb + (size_t)(c * CHUNK + i0 + (tid >> 2)) * DMEM + ((tid & 3) << 3);
      const __bf16* b1ptr =
          kvpT + (size_t)c * DMEM * DMEM + (size_t)(e0 + (tid >> 2)) * DMEM + ((tid & 3) << 3);
      const __bf16* b2ptr = memT + (size_t)(e0 + (tid >> 2)) * DMEM + ((tid & 3) << 3);
      for (int k0 = 0; k0 < DMEM; k0 += 64) {
        stage64(aptr, k0, As, wave);
        stage128(b1ptr, DMEM, k0, B1s, wave);
        stage128(b2ptr, DMEM, k0, B2s, wave);
        __syncthreads();
#pragma unroll
        for (int h = 0; h < 2; ++h) {
          bf16x8 aF[2], b1F[4], b2F[4];
#pragma unroll
          for (int i = 0; i < 2; ++i)
            aF[i] = *reinterpret_cast<const bf16x8*>(As + h * 2048 +
                                                     (wr * 32 + i * 16 + l16) * 32 + quad * 8);
#pragma unroll
          for (int j = 0; j < 4; ++j) {
            b1F[j] = *reinterpret_cast<const bf16x8*>(B1s + h * 4096 +
                                                      (wc * 64 + j * 16 + l16) * 32 + quad * 8);
            b2F[j] = *reinterpret_cast<const bf16x8*>(B2s + h * 4096 +
                                                      (wc * 64 + j * 16 + l16) * 32 + quad * 8);
          }
#pragma unroll
          for (int i = 0; i < 2; ++i)
#pragma unroll
            for (int j = 0; j < 4; ++j) {
              acc_loc[i][j] =
                  __builtin_amdgcn_mfma_f32_16x16x32_bf16(aF[i], b1F[j], acc_loc[i][j], 0, 0, 0);
              acc_mem[i][j] =
                  __builtin_amdgcn_mfma_f32_16x16x32_bf16(aF[i], b2F[j], acc_mem[i][j], 0, 0, 0);
            }
        }
        __syncthreads();
      }
    }
    float g = 1.f / (1.f + __expf(-gate[0]));
#pragma unroll
    for (int i = 0; i < 2; ++i) {
      int mb = c * CHUNK + i0 + wr * 32 + i * 16 + quad * 4;
      float dn[4], qv[4];
#pragma unroll
      for (int r = 0; r < 4; ++r) {
        dn[r] = fmaxf(den[mb + r], EPSF);
        qv[r] = fmaxf(qn[mb + r], EPSF);
      }
#pragma unroll
      for (int j = 0; j < 4; ++j) {
        int e = e0 + wc * 64 + j * 16 + l16;
#pragma unroll
        for (int r = 0; r < 4; ++r) {
          float comb = g * fl * acc_mem[i][j][r] / qv[r] + (1.f - g) * acc_loc[i][j][r] / dn[r];
          combb[(size_t)(mb + r) * DMEM + e] = (__bf16)comb;
        }
      }
    }
  } else {  // k7a: dv = v - (sk@memT)/kn -> dvT
    int t = bid - 128;
    int m0 = (t >> 1) * 128, n0 = (t & 1) * 128;
    const __bf16* aptr = skb + (size_t)(m0 + (tid >> 2)) * DMEM + ((tid & 3) << 3);
    const __bf16* bptr = memT + (size_t)(n0 + (tid >> 2)) * DMEM + ((tid & 3) << 3);
    f32x4 acc[4][4] = {};
    gemm128_bk64(aptr, DMEM, bptr, DMEM, DMEM, As, B1s, wave, wr, wc, quad, l16, acc);
#pragma unroll
    for (int i = 0; i < 4; ++i) {
      int mb = m0 + wr * 64 + i * 16 + quad * 4;
      float kv[4];
#pragma unroll
      for (int r = 0; r < 4; ++r) kv[r] = fmaxf(kn[mb + r], EPSF);
#pragma unroll
      for (int j = 0; j < 4; ++j) {
        int n = n0 + wc * 64 + j * 16 + l16;
        bf16x4 vv = *reinterpret_cast<const bf16x4*>(vT + (size_t)n * MTOT + mb);
        bf16x4 tt;
#pragma unroll
        for (int r = 0; r < 4; ++r) tt[r] = (__bf16)((float)vv[r] - acc[i][j][r] / kv[r]);
        *reinterpret_cast<bf16x4*>(dvT + (size_t)n * MTOT + mb) = tt;
      }
    }
  }
}

// ------- kF: out-proj (bid<256) + mem-update full-K (256..259) + norm (260). grid 261 ------
__global__ __launch_bounds__(256) void kF(const __bf16* __restrict__ combb,
                                          const __bf16* __restrict__ wob,
                                          const __bf16* __restrict__ skT,
                                          const __bf16* __restrict__ dvT,
                                          const float* __restrict__ mem,
                                          const float* __restrict__ ksc,
                                          const float* __restrict__ mnorm,
                                          float* __restrict__ out) {
  __shared__ __bf16 As[8192];
  __shared__ __bf16 Bs[8192];
  int tid = threadIdx.x;
  int bid = blockIdx.x;
  if (bid == 260) {  // new_memory_norm
    int d = tid;
    float s = 0.f;
    for (int c = 0; c < NCHT; ++c) s += ksc[c * DMEM + d];
    out[(size_t)MTOT * HIDDEN + DMEM * DMEM + d] = mnorm[d] + s * (1.f / (float)BATCH);
    return;
  }
  int lane = tid & 63, wave = tid >> 6;
  int wr = wave >> 1, wc = wave & 1, quad = lane >> 4, l16 = lane & 15;
  if (bid < 256) {  // k6: output projection
    int m0 = (bid & 31) * 128, by = bid >> 5;
    const __bf16* aptr = combb + (size_t)(m0 + (tid >> 2)) * DMEM + ((tid & 3) << 3);
    const __bf16* bptr = wob + (size_t)(by * 128 + (tid >> 2)) * DMEM + ((tid & 3) << 3);
    f32x4 acc[4][4] = {};
    gemm128_bk64(aptr, DMEM, bptr, DMEM, DMEM, As, Bs, wave, wr, wc, quad, l16, acc);
#pragma unroll
    for (int i = 0; i < 4; ++i)
#pragma unroll
      for (int j = 0; j < 4; ++j)
#pragma unroll
        for (int r = 0; r < 4; ++r) {
          int m = m0 + wr * 64 + i * 16 + quad * 4 + r;
          int n = by * 128 + wc * 64 + j * 16 + l16;
          out[(size_t)m * HIDDEN + n] = acc[i][j][r];
        }
  } else {  // k7b: new_memory = mem + (skT @ dvT^T)/4096, full K=4096, no atomics
    int t = bid - 256;
    int d0 = (t >> 1) * 128, e0 = (t & 1) * 128;
    const __bf16* aptr = skT + (size_t)(d0 + (tid >> 2)) * MTOT + ((tid & 3) << 3);
    const __bf16* bptr = dvT + (size_t)(e0 + (tid >> 2)) * MTOT + ((tid & 3) << 3);
    f32x4 acc[4][4] = {};
    gemm128_bk64(aptr, MTOT, bptr, MTOT, MTOT, As, Bs, wave, wr, wc, quad, l16, acc);
    float* base = out + (size_t)MTOT * HIDDEN;
#pragma unroll
    for (int i = 0; i < 4; ++i)
#pragma unroll
      for (int j = 0; j < 4; ++j)
#pragma unroll
        for (int r = 0; r < 4; ++r) {
          int d = d0 + wr * 64 + i * 16 + quad * 4 + r;
          int e = e0 + wc * 64 + j * 16 + l16;
          base[(size_t)d * DMEM + e] =
              mem[(size_t)d * DMEM + e] + acc[i][j][r] * (1.f / (float)MTOT);
        }
  }
}

extern "C" void kernel_launch(void* const* d_in, const int* in_sizes, int n_in,
                              void* d_out, int out_size, void* d_ws, size_t ws_size,
                              hipStream_t stream) {
  const float* hs = (const float*)d_in[0];
  const float* wq = (const float*)d_in[1];
  const float* wk = (const float*)d_in[2];
  const float* wv = (const float*)d_in[3];
  const float* wo = (const float*)d_in[4];
  const float* gate = (const float*)d_in[5];
  const float* mem = (const float*)d_in[6];
  const float* mnorm = (const float*)d_in[7];
  float* out = (float*)d_out;
  float* ws = (float*)d_ws;

  // fp32 region
  float* ksc = ws;          // 8192
  float* den = ksc + 8192;  // 4096
  float* qn = den + 4096;   // 4096
  float* kn = qn + 4096;    // 4096 (end 20480 floats)
  // bf16 region
  __bf16* kvcT = (__bf16*)(ws + 20480);               // 2097152
  __bf16* hsb = kvcT + (size_t)NCHT * DMEM * DMEM;    // 4194304
  __bf16* wqkvb = hsb + (size_t)MTOT * HIDDEN;        // 786432
  __bf16* wob = wqkvb + (size_t)3 * DMEM * HIDDEN;    // 262144
  __bf16* memT = wob + (size_t)HIDDEN * DMEM;         // 65536
  __bf16* sqb = memT + (size_t)DMEM * DMEM;           // 1048576
  __bf16* skb = sqb + (size_t)MTOT * DMEM;            // 1048576
  __bf16* skT = skb + (size_t)MTOT * DMEM;            // 1048576
  __bf16* vT = skT + (size_t)MTOT * DMEM;             // 1048576
  __bf16* scb = vT + (size_t)MTOT * DMEM;             // 524288
  __bf16* kvpT = scb + (size_t)NCHT * CHUNK * CHUNK;  // 2097152
  __bf16* combb = kvpT + (size_t)NCHT * DMEM * DMEM;  // 1048576
  __bf16* dvT = combb + (size_t)MTOT * DMEM;          // 1048576

  kprep<<<dim3(5136), 256, 0, stream>>>(hs, wq, wk, wv, wo, mem, hsb, wqkvb, wob, memT);
  k1_qkv_mfma<<<dim3(32, 6), 256, 0, stream>>>(hsb, wqkvb, sqb, skb, skT, vT);
  kC<<<dim3(NCHT, 7), 256, 0, stream>>>(vT, skT, sqb, skb, kvcT, scb, ksc);
  kD<<<dim3(1152), 256, 0, stream>>>(kvcT, kvpT, ksc, scb, sqb, skb, mnorm, den, qn, kn);
  kE<<<dim3(192), 256, 0, stream>>>(scb, sqb, skb, vT, kvpT, memT, den, qn, kn, gate, mnorm,
                                    combb, dvT);
  kF<<<dim3(261), 256, 0, stream>>>(combb, wob, skT, dvT, mem, ksc, mnorm, out);
}

// Round 10
// 146.328 us; speedup vs baseline: 1.4077x; 1.4077x over previous
//
#include <hip/hip_runtime.h>

// InfiniAttention — Round 10: R9 minus the k7b regression. k7b reverted to R8's
// 16-way split-K + atomics (128 blocks); mem-seed restored in kprep. BK=64 GEMMs,
// 128x128 chunk-KV, vectorized prefix kept from R9.

#define HIDDEN 1024
#define DMEM 256
#define BATCH 4
#define SEQ 1024
#define MTOT (BATCH * SEQ)      // 4096
#define CHUNK 128
#define NCH (SEQ / CHUNK)       // 8
#define NCHT (BATCH * NCH)      // 32
#define EPSF 1e-6f

typedef __bf16 bf16x8 __attribute__((ext_vector_type(8)));
typedef __bf16 bf16x4 __attribute__((ext_vector_type(4)));
typedef float f32x4 __attribute__((ext_vector_type(4)));

#define GL_LDS(g, l)                                                                   \
  __builtin_amdgcn_global_load_lds((const __attribute__((address_space(1))) void*)(g), \
                                   (__attribute__((address_space(3))) void*)(l), 16, 0, 0)

__device__ __forceinline__ float elu1(float x) { return x > 0.f ? x + 1.f : __expf(x); }

// Stage a 128-row x 64-col tile as two 32-col slabs (slab h at sm + h*4096).
__device__ __forceinline__ void stage128(const __bf16* p, long ld, int k0, __bf16* sm,
                                         int wave) {
  GL_LDS(p + k0, sm + wave * 512);
  GL_LDS(p + (size_t)64 * ld + k0, sm + 2048 + wave * 512);
  GL_LDS(p + k0 + 32, sm + 4096 + wave * 512);
  GL_LDS(p + (size_t)64 * ld + k0 + 32, sm + 4096 + 2048 + wave * 512);
}
// Stage a 64-row x 64-col tile as two slabs (slab h at sm + h*2048).
__device__ __forceinline__ void stage64(const __bf16* p, int k0, __bf16* sm, int wave) {
  GL_LDS(p + k0, sm + wave * 512);
  GL_LDS(p + k0 + 32, sm + 2048 + wave * 512);
}

// 128x128 tile, BK=64.
__device__ __forceinline__ void gemm128_bk64(const __bf16* aptr, long lda, const __bf16* bptr,
                                             long ldb, int klen, __bf16* smA, __bf16* smB,
                                             int wave, int wr, int wc, int quad, int l16,
                                             f32x4 (&acc)[4][4]) {
  for (int k0 = 0; k0 < klen; k0 += 64) {
    stage128(aptr, lda, k0, smA, wave);
    stage128(bptr, ldb, k0, smB, wave);
    __syncthreads();
#pragma unroll
    for (int h = 0; h < 2; ++h) {
      bf16x8 aF[4], bF[4];
#pragma unroll
      for (int i = 0; i < 4; ++i)
        aF[i] = *reinterpret_cast<const bf16x8*>(smA + h * 4096 +
                                                 (wr * 64 + i * 16 + l16) * 32 + quad * 8);
#pragma unroll
      for (int j = 0; j < 4; ++j)
        bF[j] = *reinterpret_cast<const bf16x8*>(smB + h * 4096 +
                                                 (wc * 64 + j * 16 + l16) * 32 + quad * 8);
#pragma unroll
      for (int i = 0; i < 4; ++i)
#pragma unroll
        for (int j = 0; j < 4; ++j)
          acc[i][j] = __builtin_amdgcn_mfma_f32_16x16x32_bf16(aF[i], bF[j], acc[i][j], 0, 0, 0);
    }
    __syncthreads();
  }
}

// 64x128 tile, BK=64.
__device__ __forceinline__ void gemm64_bk64(const __bf16* aptr, const __bf16* bptr, long ldb,
                                            int klen, __bf16* smA, __bf16* smB, int wave,
                                            int wr, int wc, int quad, int l16,
                                            f32x4 (&acc)[2][4]) {
  for (int k0 = 0; k0 < klen; k0 += 64) {
    stage64(aptr, k0, smA, wave);
    stage128(bptr, ldb, k0, smB, wave);
    __syncthreads();
#pragma unroll
    for (int h = 0; h < 2; ++h) {
      bf16x8 aF[2], bF[4];
#pragma unroll
      for (int i = 0; i < 2; ++i)
        aF[i] = *reinterpret_cast<const bf16x8*>(smA + h * 2048 +
                                                 (wr * 32 + i * 16 + l16) * 32 + quad * 8);
#pragma unroll
      for (int j = 0; j < 4; ++j)
        bF[j] = *reinterpret_cast<const bf16x8*>(smB + h * 4096 +
                                                 (wc * 64 + j * 16 + l16) * 32 + quad * 8);
#pragma unroll
      for (int i = 0; i < 2; ++i)
#pragma unroll
        for (int j = 0; j < 4; ++j)
          acc[i][j] = __builtin_amdgcn_mfma_f32_16x16x32_bf16(aF[i], bF[j], acc[i][j], 0, 0, 0);
    }
    __syncthreads();
  }
}

// ---------------- kprep: casts + memT + new_memory seed ----------------
__global__ void kprep(const float* __restrict__ hs, const float* __restrict__ wq,
                      const float* __restrict__ wk, const float* __restrict__ wv,
                      const float* __restrict__ wo, const float* __restrict__ mem,
                      __bf16* __restrict__ hsb, __bf16* __restrict__ wqkvb,
                      __bf16* __restrict__ wob, __bf16* __restrict__ memT,
                      float* __restrict__ out) {
  __shared__ float s[64][65];
  int b = blockIdx.x, tid = threadIdx.x;
  if (b < 4096) {
    int i = b * 256 + tid;
    float4 f = reinterpret_cast<const float4*>(hs)[i];
    bf16x4 h = {(__bf16)f.x, (__bf16)f.y, (__bf16)f.z, (__bf16)f.w};
    reinterpret_cast<bf16x4*>(hsb)[i] = h;
  } else if (b < 5120) {
    int y = (b - 4096) >> 8;
    const float* src = (y == 0) ? wq : (y == 1) ? wk : (y == 2) ? wv : wo;
    __bf16* dst = (y < 3) ? wqkvb + (size_t)y * (DMEM * HIDDEN) : wob;
    int i = ((b - 4096) & 255) * 256 + tid;
    float4 f = reinterpret_cast<const float4*>(src)[i];
    bf16x4 h = {(__bf16)f.x, (__bf16)f.y, (__bf16)f.z, (__bf16)f.w};
    reinterpret_cast<bf16x4*>(dst)[i] = h;
  } else if (b < 5136) {
    int t = b - 5120;
    int bx = t & 3, by = t >> 2;
    int r0 = tid >> 6, col = tid & 63;
#pragma unroll
    for (int it = 0; it < 16; ++it) {
      int row = it * 4 + r0;
      s[row][col] = mem[(size_t)(by * 64 + row) * DMEM + bx * 64 + col];
    }
    __syncthreads();
#pragma unroll
    for (int it = 0; it < 16; ++it) {
      int row = it * 4 + r0;
      memT[(size_t)(bx * 64 + row) * DMEM + by * 64 + col] = (__bf16)s[col][row];
    }
  } else {  // seed new_memory region of out with mem: 16 blocks x 256 thr x float4
    int g = (b - 5136) * 256 + tid;
    reinterpret_cast<float4*>(out + (size_t)MTOT * HIDDEN)[g] =
        reinterpret_cast<const float4*>(mem)[g];
  }
}

// ---------------- K1: fused QKV projection, 128x128 BK=64 ----------------
__global__ __launch_bounds__(256) void k1_qkv_mfma(
    const __bf16* __restrict__ X, const __bf16* __restrict__ W, __bf16* __restrict__ sqb,
    __bf16* __restrict__ skb, __bf16* __restrict__ skT, __bf16* __restrict__ vT) {
  __shared__ __bf16 As[8192];
  __shared__ __bf16 Bs[8192];
  int tid = threadIdx.x;
  int lane = tid & 63, wave = tid >> 6;
  int m0 = blockIdx.x * 128;
  int by = blockIdx.y;
  int wsel = by >> 1, n0 = (by & 1) * 128;
  const __bf16* aptr = X + (size_t)(m0 + (tid >> 2)) * HIDDEN + ((tid & 3) << 3);
  const __bf16* bptr = W + (size_t)(by * 128 + (tid >> 2)) * HIDDEN + ((tid & 3) << 3);
  int wr = wave >> 1, wc = wave & 1, quad = lane >> 4, l16 = lane & 15;
  f32x4 acc[4][4] = {};
  gemm128_bk64(aptr, HIDDEN, bptr, HIDDEN, HIDDEN, As, Bs, wave, wr, wc, quad, l16, acc);
#pragma unroll
  for (int i = 0; i < 4; ++i)
#pragma unroll
    for (int j = 0; j < 4; ++j) {
      int mb = m0 + wr * 64 + i * 16 + quad * 4;
      int n = n0 + wc * 64 + j * 16 + l16;
      if (wsel == 0) {
#pragma unroll
        for (int r = 0; r < 4; ++r) sqb[(size_t)(mb + r) * DMEM + n] = (__bf16)elu1(acc[i][j][r]);
      } else if (wsel == 1) {
        bf16x4 t;
#pragma unroll
        for (int r = 0; r < 4; ++r) {
          float v = elu1(acc[i][j][r]);
          skb[(size_t)(mb + r) * DMEM + n] = (__bf16)v;
          t[r] = (__bf16)v;
        }
        *reinterpret_cast<bf16x4*>(skT + (size_t)n * MTOT + mb) = t;
      } else {
        bf16x4 t;
#pragma unroll
        for (int r = 0; r < 4; ++r) t[r] = (__bf16)acc[i][j][r];
        *reinterpret_cast<bf16x4*>(vT + (size_t)n * MTOT + mb) = t;
      }
    }
}

// ------- kC: chunk-KV 128x128 (y<4) + causal scores (y=4,5) + ksum (y=6). grid (32,7) ------
__global__ __launch_bounds__(256) void kC(const __bf16* __restrict__ vT,
                                          const __bf16* __restrict__ skT,
                                          const __bf16* __restrict__ sqb,
                                          const __bf16* __restrict__ skb,
                                          __bf16* __restrict__ kvcT, __bf16* __restrict__ scb,
                                          float* __restrict__ ksc) {
  __shared__ __bf16 As[8192];
  __shared__ __bf16 Bs[8192];
  int tid = threadIdx.x;
  int c = blockIdx.x;
  int y = blockIdx.y;
  if (y == 6) {
    int d = tid;
    float s = 0.f;
    for (int i = 0; i < CHUNK; ++i) s += (float)skb[(size_t)(c * CHUNK + i) * DMEM + d];
    ksc[c * DMEM + d] = s;
    return;
  }
  int lane = tid & 63, wave = tid >> 6;
  int wr = wave >> 1, wc = wave & 1, quad = lane >> 4, l16 = lane & 15;
  if (y < 4) {  // kvcT[c][e][d] = sum_s vT[e,s]*skT[d,s], 128x128 tile
    int e0 = (y >> 1) * 128, d0 = (y & 1) * 128;
    const __bf16* aptr = vT + (size_t)(e0 + (tid >> 2)) * MTOT + c * CHUNK + ((tid & 3) << 3);
    const __bf16* bptr = skT + (size_t)(d0 + (tid >> 2)) * MTOT + c * CHUNK + ((tid & 3) << 3);
    f32x4 acc[4][4] = {};
    gemm128_bk64(aptr, MTOT, bptr, MTOT, CHUNK, As, Bs, wave, wr, wc, quad, l16, acc);
#pragma unroll
    for (int i = 0; i < 4; ++i)
#pragma unroll
      for (int j = 0; j < 4; ++j)
#pragma unroll
        for (int r = 0; r < 4; ++r) {
          int e = e0 + wr * 64 + i * 16 + quad * 4 + r;
          int d = d0 + wc * 64 + j * 16 + l16;
          kvcT[(size_t)c * DMEM * DMEM + (size_t)e * DMEM + d] = (__bf16)acc[i][j][r];
        }
  } else {  // causal scores, i0 = (y-4)*64
    int i0 = (y - 4) * 64;
    const __bf16* aptr = sqb + (size_t)(c * CHUNK + i0 + (tid >> 2)) * DMEM + ((tid & 3) << 3);
    const __bf16* bptr = skb + (size_t)(c * CHUNK + (tid >> 2)) * DMEM + ((tid & 3) << 3);
    f32x4 acc[2][4] = {};
    gemm64_bk64(aptr, bptr, DMEM, DMEM, As, Bs, wave, wr, wc, quad, l16, acc);
#pragma unroll
    for (int i = 0; i < 2; ++i)
#pragma unroll
      for (int j = 0; j < 4; ++j)
#pragma unroll
        for (int r = 0; r < 4; ++r) {
          int ii = i0 + wr * 32 + i * 16 + quad * 4 + r;
          int jj = wc * 64 + j * 16 + l16;
          scb[(size_t)c * CHUNK * CHUNK + (size_t)ii * CHUNK + jj] =
              (jj <= ii) ? (__bf16)acc[i][j][r] : (__bf16)0.f;
        }
  }
}

// ---------------- kD: vectorized prefix (vt<128) + row scalars (vt>=128). grid 1152 -------
__global__ __launch_bounds__(256) void kD(const __bf16* __restrict__ kvcT,
                                          __bf16* __restrict__ kvpT,
                                          const float* __restrict__ ksc,
                                          const __bf16* __restrict__ scb,
                                          const __bf16* __restrict__ sqb,
                                          const __bf16* __restrict__ skb,
                                          const float* __restrict__ mnorm,
                                          float* __restrict__ den, float* __restrict__ qn,
                                          float* __restrict__ kn) {
  int vt = blockIdx.x;
  int tid = threadIdx.x;
  if (vt < 128) {
    int batch = vt >> 5;
    size_t idx8 = (size_t)(((vt & 31) * 256 + tid)) * 8;
    float run[8] = {};
    for (int c = 0; c < NCH; ++c) {
      size_t off = (size_t)(batch * NCH + c) * DMEM * DMEM + idx8;
      bf16x8 t = *reinterpret_cast<const bf16x8*>(kvcT + off);
      bf16x8 o;
#pragma unroll
      for (int r = 0; r < 8; ++r) o[r] = (__bf16)run[r];
      *reinterpret_cast<bf16x8*>(kvpT + off) = o;
#pragma unroll
      for (int r = 0; r < 8; ++r) run[r] += (float)t[r];
    }
  } else {
    int wave = tid >> 6, lane = tid & 63;
    int m = (vt - 128) * 4 + wave;
    int c = m >> 7;
    int i = m & 127;
    int cb = c & ~7;
    float s_sc = 0.f, s_d2 = 0.f, s_qn = 0.f, s_kn = 0.f;
    for (int j = lane; j < CHUNK; j += 64)
      s_sc += (float)scb[(size_t)c * CHUNK * CHUNK + (size_t)i * CHUNK + j];
    for (int d = lane; d < DMEM; d += 64) {
      float q = (float)sqb[(size_t)m * DMEM + d];
      float k = (float)skb[(size_t)m * DMEM + d];
      float kp = 0.f;
      for (int cc = cb; cc < c; ++cc) kp += ksc[cc * DMEM + d];
      s_d2 += q * kp;
      s_qn += q * mnorm[d];
      s_kn += k * mnorm[d];
    }
#pragma unroll
    for (int off = 32; off > 0; off >>= 1) {
      s_sc += __shfl_down(s_sc, off);
      s_d2 += __shfl_down(s_d2, off);
      s_qn += __shfl_down(s_qn, off);
      s_kn += __shfl_down(s_kn, off);
    }
    if (lane == 0) {
      den[m] = s_sc + s_d2;
      qn[m] = s_qn;
      kn[m] = s_kn;
    }
  }
}

// ---------------- kE: combine (bid<128) + delta-v (128..191). grid 192 ----------------
__global__ __launch_bounds__(256) void kE(const __bf16* __restrict__ scb,
                                          const __bf16* __restrict__ sqb,
                                          const __bf16* __restrict__ skb,
                                          const __bf16* __restrict__ vT,
                                          const __bf16* __restrict__ kvpT,
                                          const __bf16* __restrict__ memT,
                                          const float* __restrict__ den,
                                          const float* __restrict__ qn,
                                          const float* __restrict__ kn,
                                          const float* __restrict__ gate,
                                          const float* __restrict__ mnorm,
                                          __bf16* __restrict__ combb, __bf16* __restrict__ dvT) {
  __shared__ __bf16 As[8192];
  __shared__ __bf16 B1s[8192];
  __shared__ __bf16 B2s[8192];
  __shared__ float flagsh;
  int tid = threadIdx.x;
  int lane = tid & 63, wave = tid >> 6;
  int wr = wave >> 1, wc = wave & 1, quad = lane >> 4, l16 = lane & 15;
  int bid = blockIdx.x;
  if (bid < 128) {  // combine
    if (tid == 0) {
      float s = 0.f;
      for (int d = 0; d < DMEM; ++d) s += mnorm[d];
      flagsh = (s < EPSF) ? 0.f : 1.f;
    }
    __syncthreads();
    float fl = flagsh;
    __syncthreads();
    int c = bid >> 2, yy = bid & 3;
    int i0 = (yy >> 1) * 64, e0 = (yy & 1) * 128;
    f32x4 acc_loc[2][4] = {};
    f32x4 acc_mem[2][4] = {};
    {  // phase 1: scores @ v (K=128)
      const __bf16* aptr =
          scb + (size_t)c * CHUNK * CHUNK + (size_t)(i0 + (tid >> 2)) * CHUNK + ((tid & 3) << 3);
      const __bf16* bptr = vT + (size_t)(e0 + (tid >> 2)) * MTOT + c * CHUNK + ((tid & 3) << 3);
      gemm64_bk64(aptr, bptr, MTOT, CHUNK, As, B1s, wave, wr, wc, quad, l16, acc_loc);
    }
    {  // phase 2: sq @ kvp + sq @ memT (K=256, dual B)
      const __bf16* aptr = sqb + (size_t)(c * CHUNK + i0 + (tid >> 2)) * DMEM + ((tid & 3) << 3);
      const __bf16* b1ptr =
          kvpT + (size_t)c * DMEM * DMEM + (size_t)(e0 + (tid >> 2)) * DMEM + ((tid & 3) << 3);
      const __bf16* b2ptr = memT + (size_t)(e0 + (tid >> 2)) * DMEM + ((tid & 3) << 3);
      for (int k0 = 0; k0 < DMEM; k0 += 64) {
        stage64(aptr, k0, As, wave);
        stage128(b1ptr, DMEM, k0, B1s, wave);
        stage128(b2ptr, DMEM, k0, B2s, wave);
        __syncthreads();
#pragma unroll
        for (int h = 0; h < 2; ++h) {
          bf16x8 aF[2], b1F[4], b2F[4];
#pragma unroll
          for (int i = 0; i < 2; ++i)
            aF[i] = *reinterpret_cast<const bf16x8*>(As + h * 2048 +
                                                     (wr * 32 + i * 16 + l16) * 32 + quad * 8);
#pragma unroll
          for (int j = 0; j < 4; ++j) {
            b1F[j] = *reinterpret_cast<const bf16x8*>(B1s + h * 4096 +
                                                      (wc * 64 + j * 16 + l16) * 32 + quad * 8);
            b2F[j] = *reinterpret_cast<const bf16x8*>(B2s + h * 4096 +
                                                      (wc * 64 + j * 16 + l16) * 32 + quad * 8);
          }
#pragma unroll
          for (int i = 0; i < 2; ++i)
#pragma unroll
            for (int j = 0; j < 4; ++j) {
              acc_loc[i][j] =
                  __builtin_amdgcn_mfma_f32_16x16x32_bf16(aF[i], b1F[j], acc_loc[i][j], 0, 0, 0);
              acc_mem[i][j] =
                  __builtin_amdgcn_mfma_f32_16x16x32_bf16(aF[i], b2F[j], acc_mem[i][j], 0, 0, 0);
            }
        }
        __syncthreads();
      }
    }
    float g = 1.f / (1.f + __expf(-gate[0]));
#pragma unroll
    for (int i = 0; i < 2; ++i) {
      int mb = c * CHUNK + i0 + wr * 32 + i * 16 + quad * 4;
      float dn[4], qv[4];
#pragma unroll
      for (int r = 0; r < 4; ++r) {
        dn[r] = fmaxf(den[mb + r], EPSF);
        qv[r] = fmaxf(qn[mb + r], EPSF);
      }
#pragma unroll
      for (int j = 0; j < 4; ++j) {
        int e = e0 + wc * 64 + j * 16 + l16;
#pragma unroll
        for (int r = 0; r < 4; ++r) {
          float comb = g * fl * acc_mem[i][j][r] / qv[r] + (1.f - g) * acc_loc[i][j][r] / dn[r];
          combb[(size_t)(mb + r) * DMEM + e] = (__bf16)comb;
        }
      }
    }
  } else {  // k7a: dv = v - (sk@memT)/kn -> dvT
    int t = bid - 128;
    int m0 = (t >> 1) * 128, n0 = (t & 1) * 128;
    const __bf16* aptr = skb + (size_t)(m0 + (tid >> 2)) * DMEM + ((tid & 3) << 3);
    const __bf16* bptr = memT + (size_t)(n0 + (tid >> 2)) * DMEM + ((tid & 3) << 3);
    f32x4 acc[4][4] = {};
    gemm128_bk64(aptr, DMEM, bptr, DMEM, DMEM, As, B1s, wave, wr, wc, quad, l16, acc);
#pragma unroll
    for (int i = 0; i < 4; ++i) {
      int mb = m0 + wr * 64 + i * 16 + quad * 4;
      float kv[4];
#pragma unroll
      for (int r = 0; r < 4; ++r) kv[r] = fmaxf(kn[mb + r], EPSF);
#pragma unroll
      for (int j = 0; j < 4; ++j) {
        int n = n0 + wc * 64 + j * 16 + l16;
        bf16x4 vv = *reinterpret_cast<const bf16x4*>(vT + (size_t)n * MTOT + mb);
        bf16x4 tt;
#pragma unroll
        for (int r = 0; r < 4; ++r) tt[r] = (__bf16)((float)vv[r] - acc[i][j][r] / kv[r]);
        *reinterpret_cast<bf16x4*>(dvT + (size_t)n * MTOT + mb) = tt;
      }
    }
  }
}

// -- kF: out-proj (bid<256) + mem-update split-K atomics (256..383) + norm (384). grid 385 --
__global__ __launch_bounds__(256) void kF(const __bf16* __restrict__ combb,
                                          const __bf16* __restrict__ wob,
                                          const __bf16* __restrict__ skT,
                                          const __bf16* __restrict__ dvT,
                                          const float* __restrict__ ksc,
                                          const float* __restrict__ mnorm,
                                          float* __restrict__ out) {
  __shared__ __bf16 As[8192];
  __shared__ __bf16 Bs[8192];
  int tid = threadIdx.x;
  int bid = blockIdx.x;
  if (bid == 384) {  // new_memory_norm
    int d = tid;
    float s = 0.f;
    for (int c = 0; c < NCHT; ++c) s += ksc[c * DMEM + d];
    out[(size_t)MTOT * HIDDEN + DMEM * DMEM + d] = mnorm[d] + s * (1.f / (float)BATCH);
    return;
  }
  int lane = tid & 63, wave = tid >> 6;
  int wr = wave >> 1, wc = wave & 1, quad = lane >> 4, l16 = lane & 15;
  if (bid < 256) {  // k6: output projection, 128x128 BK=64
    int m0 = (bid & 31) * 128, by = bid >> 5;
    const __bf16* aptr = combb + (size_t)(m0 + (tid >> 2)) * DMEM + ((tid & 3) << 3);
    const __bf16* bptr = wob + (size_t)(by * 128 + (tid >> 2)) * DMEM + ((tid & 3) << 3);
    f32x4 acc[4][4] = {};
    gemm128_bk64(aptr, DMEM, bptr, DMEM, DMEM, As, Bs, wave, wr, wc, quad, l16, acc);
#pragma unroll
    for (int i = 0; i < 4; ++i)
#pragma unroll
      for (int j = 0; j < 4; ++j)
#pragma unroll
        for (int r = 0; r < 4; ++r) {
          int m = m0 + wr * 64 + i * 16 + quad * 4 + r;
          int n = by * 128 + wc * 64 + j * 16 + l16;
          out[(size_t)m * HIDDEN + n] = acc[i][j][r];
        }
  } else {  // k7b: 16-way split-K (K=256 each), 64x128 tiles, atomics (R8-proven)
    int t = bid - 256;
    int kbase = (t >> 3) * 256;
    int yy = t & 7;
    int d0 = (yy >> 1) * 64, e0 = (yy & 1) * 128;
    const __bf16* aptr = skT + (size_t)(d0 + (tid >> 2)) * MTOT + kbase + ((tid & 3) << 3);
    const __bf16* bptr = dvT + (size_t)(e0 + (tid >> 2)) * MTOT + kbase + ((tid & 3) << 3);
    f32x4 acc[2][4] = {};
    gemm64_bk64(aptr, bptr, MTOT, 256, As, Bs, wave, wr, wc, quad, l16, acc);
    float* base = out + (size_t)MTOT * HIDDEN;
#pragma unroll
    for (int i = 0; i < 2; ++i)
#pragma unroll
      for (int j = 0; j < 4; ++j)
#pragma unroll
        for (int r = 0; r < 4; ++r) {
          int d = d0 + wr * 32 + i * 16 + quad * 4 + r;
          int e = e0 + wc * 64 + j * 16 + l16;
          atomicAdd(&base[(size_t)d * DMEM + e], acc[i][j][r] * (1.f / (float)MTOT));
        }
  }
}

extern "C" void kernel_launch(void* const* d_in, const int* in_sizes, int n_in,
                              void* d_out, int out_size, void* d_ws, size_t ws_size,
                              hipStream_t stream) {
  const float* hs = (const float*)d_in[0];
  const float* wq = (const float*)d_in[1];
  const float* wk = (const float*)d_in[2];
  const float* wv = (const float*)d_in[3];
  const float* wo = (const float*)d_in[4];
  const float* gate = (const float*)d_in[5];
  const float* mem = (const float*)d_in[6];
  const float* mnorm = (const float*)d_in[7];
  float* out = (float*)d_out;
  float* ws = (float*)d_ws;

  // fp32 region
  float* ksc = ws;          // 8192
  float* den = ksc + 8192;  // 4096
  float* qn = den + 4096;   // 4096
  float* kn = qn + 4096;    // 4096 (end 20480 floats)
  // bf16 region
  __bf16* kvcT = (__bf16*)(ws + 20480);               // 2097152
  __bf16* hsb = kvcT + (size_t)NCHT * DMEM * DMEM;    // 4194304
  __bf16* wqkvb = hsb + (size_t)MTOT * HIDDEN;        // 786432
  __bf16* wob = wqkvb + (size_t)3 * DMEM * HIDDEN;    // 262144
  __bf16* memT = wob + (size_t)HIDDEN * DMEM;         // 65536
  __bf16* sqb = memT + (size_t)DMEM * DMEM;           // 1048576
  __bf16* skb = sqb + (size_t)MTOT * DMEM;            // 1048576
  __bf16* skT = skb + (size_t)MTOT * DMEM;            // 1048576
  __bf16* vT = skT + (size_t)MTOT * DMEM;             // 1048576
  __bf16* scb = vT + (size_t)MTOT * DMEM;             // 524288
  __bf16* kvpT = scb + (size_t)NCHT * CHUNK * CHUNK;  // 2097152
  __bf16* combb = kvpT + (size_t)NCHT * DMEM * DMEM;  // 1048576
  __bf16* dvT = combb + (size_t)MTOT * DMEM;          // 1048576

  kprep<<<dim3(5152), 256, 0, stream>>>(hs, wq, wk, wv, wo, mem, hsb, wqkvb, wob, memT, out);
  k1_qkv_mfma<<<dim3(32, 6), 256, 0, stream>>>(hsb, wqkvb, sqb, skb, skT, vT);
  kC<<<dim3(NCHT, 7), 256, 0, stream>>>(vT, skT, sqb, skb, kvcT, scb, ksc);
  kD<<<dim3(1152), 256, 0, stream>>>(kvcT, kvpT, ksc, scb, sqb, skb, mnorm, den, qn, kn);
  kE<<<dim3(192), 256, 0, stream>>>(scb, sqb, skb, vT, kvpT, memT, den, qn, kn, gate, mnorm,
                                    combb, dvT);
  kF<<<dim3(385), 256, 0, stream>>>(combb, wob, skT, dvT, ksc, mnorm, out);
}